// Round 10
// baseline (211.540 us; speedup 1.0000x reference)
//
#include <hip/hip_runtime.h>
#include <math.h>

typedef __bf16 bf16x8 __attribute__((ext_vector_type(8)));
typedef float f32x4 __attribute__((ext_vector_type(4)));

__device__ __forceinline__ unsigned f2bf(float f) {
    union { float f; unsigned u; } v; v.f = f;
    return (v.u + 0x7FFFu + ((v.u >> 16) & 1u)) >> 16;
}

// packed fp32->bf16 (RNE), 2 values in 1 op: lo=a, hi=b
__device__ __forceinline__ unsigned cvtpk(float a, float b) {
    unsigned r;
    __asm__("v_cvt_pk_bf16_f32 %0, %1, %2" : "=v"(r) : "v"(a), "v"(b));
    return r;
}

// async global->LDS, 16B per lane. LDS dest = wave-uniform base + lane*16.
__device__ __forceinline__ void gload16(const ushort* g, ushort* l) {
    __builtin_amdgcn_global_load_lds(
        (const __attribute__((address_space(1))) void*)g,
        (__attribute__((address_space(3))) void*)l, 16, 0, 0);
}

// ---------------------------------------------------------------------------
// Fused input canonicalization (one launch): fp32 -> bf16 for all 3 inputs.
// ---------------------------------------------------------------------------
__device__ __forceinline__ bool src_is_fp32(const unsigned* s) {
    int sane = 0;
#pragma unroll
    for (int i = 0; i < 64; ++i) {
        unsigned lo = s[i] & 0xFFFFu;
        unsigned e = (lo >> 7) & 0xFF;
        if (lo == 0u || (e >= 100u && e <= 140u)) sane++;
    }
    return sane < 48;
}

__global__ __launch_bounds__(256) void tobf16_all_kernel(
    const unsigned* __restrict__ s0, const unsigned* __restrict__ s1,
    const unsigned* __restrict__ s2,
    ushort* __restrict__ d0, ushort* __restrict__ d1, ushort* __restrict__ d2) {
    const int bx = blockIdx.x;
    const unsigned* src;
    ushort* dst;
    int lb;
    if (bx < 2048)      { src = s0; dst = d0; lb = bx; }
    else if (bx < 3584) { src = s1; dst = d1; lb = bx - 2048; }
    else                { src = s2; dst = d2; lb = bx - 3584; }
    const int i = lb * 2048 + threadIdx.x * 8;
    if (src_is_fp32(src)) {
        const float* fs = (const float*)src;
        float4 f0 = *(const float4*)(fs + i);
        float4 f1 = *(const float4*)(fs + i + 4);
        uint4 o;
        o.x = f2bf(f0.x) | (f2bf(f0.y) << 16);
        o.y = f2bf(f0.z) | (f2bf(f0.w) << 16);
        o.z = f2bf(f1.x) | (f2bf(f1.y) << 16);
        o.w = f2bf(f1.z) | (f2bf(f1.w) << 16);
        *(uint4*)(dst + i) = o;
    } else {
        *(uint4*)(dst + i) = *(const uint4*)((const ushort*)src + i);
    }
}

// ---------------------------------------------------------------------------
// GEMM K-loop: double-buffered LDS + global_load_lds issued one compute-phase
// ahead of its consuming barrier (validated win, round 10).
// ---------------------------------------------------------------------------
constexpr int GBM = 128, GBN = 128, GBK = 32;

// ---- GEMM1 + RoPE + head-major remap; V written TRANSPOSED [b][h][d][t] ---
__global__ __launch_bounds__(256) void gemm_qkv_rope_kernel(
    const ushort* __restrict__ A, const ushort* __restrict__ Bmat,
    ushort* __restrict__ qkvh, int K) {
    __shared__ ushort As[2][GBM * GBK];
    __shared__ ushort Bs[2][GBN * GBK];

    const int tid  = threadIdx.x;
    const int lane = tid & 63;
    const int wv   = tid >> 6;
    const int wm   = (wv >> 1) * 64;
    const int wn   = (wv & 1) * 64;

    const ushort* Ab = A + (size_t)blockIdx.x * GBM * K;
    const ushort* Bb = Bmat + (size_t)blockIdx.y * GBN * K;

    f32x4 acc[4][4];
#pragma unroll
    for (int i = 0; i < 4; i++)
#pragma unroll
        for (int j = 0; j < 4; j++) acc[i][j] = (f32x4){0.f, 0.f, 0.f, 0.f};

    const int srow = tid >> 2;
    const int scol = (tid & 3) * 8;
    const int fr = lane & 15;
    const int fk = (lane >> 4) * 8;
    const int nK = K >> 5;

    gload16(Ab + (size_t)srow * K + scol,        As[0] + wv * 512);
    gload16(Ab + (size_t)(srow + 64) * K + scol, As[0] + wv * 512 + 2048);
    gload16(Bb + (size_t)srow * K + scol,        Bs[0] + wv * 512);
    gload16(Bb + (size_t)(srow + 64) * K + scol, Bs[0] + wv * 512 + 2048);

#pragma unroll 1
    for (int it = 0; it < nK; ++it) {
        const int cur = it & 1;
        __syncthreads();
        if (it + 1 < nK) {
            const int k0 = (it + 1) << 5, nxt = cur ^ 1;
            gload16(Ab + (size_t)srow * K + k0 + scol,        As[nxt] + wv * 512);
            gload16(Ab + (size_t)(srow + 64) * K + k0 + scol, As[nxt] + wv * 512 + 2048);
            gload16(Bb + (size_t)srow * K + k0 + scol,        Bs[nxt] + wv * 512);
            gload16(Bb + (size_t)(srow + 64) * K + k0 + scol, Bs[nxt] + wv * 512 + 2048);
        }
        bf16x8 af[4], bfr[4];
#pragma unroll
        for (int i = 0; i < 4; i++)
            af[i] = *(const bf16x8*)(As[cur] + (wm + i * 16 + fr) * GBK + fk);
#pragma unroll
        for (int j = 0; j < 4; j++)
            bfr[j] = *(const bf16x8*)(Bs[cur] + (wn + j * 16 + fr) * GBK + fk);
#pragma unroll
        for (int i = 0; i < 4; i++)
#pragma unroll
            for (int j = 0; j < 4; j++)
                acc[i][j] = __builtin_amdgcn_mfma_f32_16x16x32_bf16(af[i], bfr[j], acc[i][j], 0, 0, 0);
    }

    const int crow0 = (lane >> 4) * 4;
    const int col0  = blockIdx.y * GBN + wn;       // 64-aligned
    const int which = col0 >> 10;                  // 0=q 1=k 2=v
    const int hh    = (col0 >> 6) & 15;

    if (which < 2) {
        ushort* outp = qkvh + (size_t)which * 4194304 + (size_t)hh * 131072;
        const float inva = exp2f((float)fr * -0.41524101186f);
        const float invb = exp2f((float)(fr + 16) * -0.41524101186f);
        const float qs = (which == 0) ? 0.125f : 1.0f;
#pragma unroll
        for (int i = 0; i < 4; i++)
#pragma unroll
            for (int r = 0; r < 4; r++) {
                int row = blockIdx.x * GBM + wm + i * 16 + crow0 + r;
                int t = row & 2047;
                size_t ob = ((size_t)(row >> 11)) * 2097152 + (size_t)t * 64;
                float sa, ca, sb, cb;
                __sincosf((float)t * inva, &sa, &ca);
                __sincosf((float)t * invb, &sb, &cb);
                float q0 = acc[i][0][r], q1 = acc[i][1][r];
                float q2 = acc[i][2][r], q3 = acc[i][3][r];
                float n0 = (q0 * ca + q2 * sa) * qs;
                float n1 = (q1 * cb + q3 * sb) * qs;
                float n2 = (q2 * ca - q0 * sa) * qs;
                float n3 = (q3 * cb - q1 * sb) * qs;
                unsigned u01 = cvtpk(n0, n1);
                unsigned u23 = cvtpk(n2, n3);
                outp[ob + fr]      = (ushort)(u01 & 0xFFFFu);
                outp[ob + 16 + fr] = (ushort)(u01 >> 16);
                outp[ob + 32 + fr] = (ushort)(u23 & 0xFFFFu);
                outp[ob + 48 + fr] = (ushort)(u23 >> 16);
            }
    } else {
        // V: transposed layout [b][h][d=64][t=2048]; 4 consecutive t packed
        const int row0 = blockIdx.x * GBM;   // whole block in one b
        ushort* vout = qkvh + (size_t)2 * 4194304
                     + ((size_t)(row0 >> 11)) * 2097152 + (size_t)hh * 131072;
#pragma unroll
        for (int i = 0; i < 4; i++) {
            const int t0 = (blockIdx.x * GBM + wm + i * 16 + crow0) & 2047;
#pragma unroll
            for (int j = 0; j < 4; j++) {
                uint2 u;
                u.x = cvtpk(acc[i][j][0], acc[i][j][1]);
                u.y = cvtpk(acc[i][j][2], acc[i][j][3]);
                *(uint2*)(vout + (size_t)(j * 16 + fr) * 2048 + t0) = u;
            }
        }
    }
}

// ---- out-projection GEMM (fp32 out), same dbuf loop -----------------------
__global__ __launch_bounds__(256) void gemm_bt_kernel(
    const ushort* __restrict__ A, const ushort* __restrict__ Bmat,
    float* __restrict__ C, int M, int N, int K) {
    __shared__ ushort As[2][GBM * GBK];
    __shared__ ushort Bs[2][GBN * GBK];

    const int tid  = threadIdx.x;
    const int lane = tid & 63;
    const int wv   = tid >> 6;
    const int wm   = (wv >> 1) * 64;
    const int wn   = (wv & 1) * 64;

    const ushort* Ab = A + (size_t)blockIdx.x * GBM * K;
    const ushort* Bb = Bmat + (size_t)blockIdx.y * GBN * K;

    f32x4 acc[4][4];
#pragma unroll
    for (int i = 0; i < 4; i++)
#pragma unroll
        for (int j = 0; j < 4; j++) acc[i][j] = (f32x4){0.f, 0.f, 0.f, 0.f};

    const int srow = tid >> 2;
    const int scol = (tid & 3) * 8;
    const int fr = lane & 15;
    const int fk = (lane >> 4) * 8;
    const int nK = K >> 5;

    gload16(Ab + (size_t)srow * K + scol,        As[0] + wv * 512);
    gload16(Ab + (size_t)(srow + 64) * K + scol, As[0] + wv * 512 + 2048);
    gload16(Bb + (size_t)srow * K + scol,        Bs[0] + wv * 512);
    gload16(Bb + (size_t)(srow + 64) * K + scol, Bs[0] + wv * 512 + 2048);

#pragma unroll 1
    for (int it = 0; it < nK; ++it) {
        const int cur = it & 1;
        __syncthreads();
        if (it + 1 < nK) {
            const int k0 = (it + 1) << 5, nxt = cur ^ 1;
            gload16(Ab + (size_t)srow * K + k0 + scol,        As[nxt] + wv * 512);
            gload16(Ab + (size_t)(srow + 64) * K + k0 + scol, As[nxt] + wv * 512 + 2048);
            gload16(Bb + (size_t)srow * K + k0 + scol,        Bs[nxt] + wv * 512);
            gload16(Bb + (size_t)(srow + 64) * K + k0 + scol, Bs[nxt] + wv * 512 + 2048);
        }
        bf16x8 af[4], bfr[4];
#pragma unroll
        for (int i = 0; i < 4; i++)
            af[i] = *(const bf16x8*)(As[cur] + (wm + i * 16 + fr) * GBK + fk);
#pragma unroll
        for (int j = 0; j < 4; j++)
            bfr[j] = *(const bf16x8*)(Bs[cur] + (wn + j * 16 + fr) * GBK + fk);
#pragma unroll
        for (int i = 0; i < 4; i++)
#pragma unroll
            for (int j = 0; j < 4; j++)
                acc[i][j] = __builtin_amdgcn_mfma_f32_16x16x32_bf16(af[i], bfr[j], acc[i][j], 0, 0, 0);
    }

    const int crow0 = (lane >> 4) * 4;
#pragma unroll
    for (int i = 0; i < 4; i++)
#pragma unroll
        for (int j = 0; j < 4; j++)
#pragma unroll
            for (int r = 0; r < 4; r++) {
                int row = blockIdx.x * GBM + wm + i * 16 + crow0 + r;
                int col = blockIdx.y * GBN + wn + j * 16 + fr;
                C[(size_t)row * N + col] = acc[i][j][r];
            }
}

// ---------------------------------------------------------------------------
// Causal flash attention v16: barrier-free main loop (L2-direct K/V).
// r9's XCD swizzle made per-XCD K/V footprint 2 MB (L2-resident). So:
//  - K and V fragments read DIRECTLY global->VGPR (plain b128, L2 hits);
//    no LDS staging, no dbuf, no per-iter __syncthreads. Waves run fully
//    async; pipe phases de-correlate (the ~40% barrier-serialization
//    stall in v15's model disappears).
//  - Index semantics = v15's unswizzled reads verbatim:
//      kf0/kf1 = K[key][fk / fk+32],  key = k0+(jb+jl)*16+fr
//      vf      = V^T[j4*16+fr][k0 + half*64 + kl*32 + fk]
//  - Ps round-trip (per-wave private) + mask + epilogue unchanged (v13/v15
//    validated). LDS = Ps only: 36864 B (exchange region reuses it).
//  - diagonal iter: waves (half=1, wq<2) fully masked -> skip outright.
// ---------------------------------------------------------------------------
#define NEG_BIG (-1e30f)
constexpr int LPP = 72;       // Ps row: 64 keys + 8 pad

__global__ __launch_bounds__(512) void attn_kernel(const ushort* __restrict__ qkvh,
                                                   ushort* __restrict__ y) {
    __shared__ ushort SM[8 * 32 * LPP];   // 18432 ushorts = 36864 B

    const int tid  = threadIdx.x;
    const int lane = tid & 63;
    const int wv   = tid >> 6;          // 0..7
    const int half = wv >> 2;           // 0: keys 0..63, 1: keys 64..127
    const int wq   = wv & 3;            // 32-row q-group
    const int jb   = half * 4;          // key-tile base

    // T1: bijective XCD swizzle (grid (8,32) -> 256 blocks, XCD = id&7)
    const int id   = blockIdx.x + (blockIdx.y << 3);
    const int xcd  = id & 7;
    const int k8   = id >> 3;           // 0..31
    const int bh   = xcd * 4 + (k8 & 3);
    const int pid  = k8 >> 2;           // 0..7
    const int b    = bh >> 4, h = bh & 15;

    const ushort* qp = qkvh + (size_t)b * 2097152 + (size_t)h * 131072;
    const ushort* kp = qp + 4194304;    // K [t][64]
    const ushort* vp = qp + 8388608;    // V^T [d][2048]

    const int fr = lane & 15;
    const int fq = lane >> 4;
    const int fk = fq * 8;

    ushort* pw = SM + wv * (32 * LPP);

#pragma unroll 1
    for (int seg = 0; seg < 2; ++seg) {
        const int qb = seg ? (15 - pid) : pid;    // 128-row q-block, 0..15
        const int nIt = qb + 1;

        __syncthreads();   // previous seg epilogue exchange reads done (Ps reuse)

        const int qrowA = qb * 128 + wq * 32 + fr;
        bf16x8 qfA0 = *(const bf16x8*)(qp + (size_t)qrowA * 64 + fk);
        bf16x8 qfA1 = *(const bf16x8*)(qp + (size_t)qrowA * 64 + 32 + fk);
        bf16x8 qfB0 = *(const bf16x8*)(qp + (size_t)(qrowA + 16) * 64 + fk);
        bf16x8 qfB1 = *(const bf16x8*)(qp + (size_t)(qrowA + 16) * 64 + 32 + fk);

        f32x4 oA[4], oB[4];
#pragma unroll
        for (int j4 = 0; j4 < 4; ++j4) {
            oA[j4] = (f32x4){0.f, 0.f, 0.f, 0.f};
            oB[j4] = (f32x4){0.f, 0.f, 0.f, 0.f};
        }
        float lsumA = 0.f, lsumB = 0.f;

#pragma unroll 1
        for (int it = 0; it < nIt; ++it) {
            const int k0 = it * 128;
            const bool lastIt = (it + 1 == nIt);
            // diagonal iter: keys 64..127 > all rows of wq<2 strips -> skip
            if (lastIt && half && (wq < 2)) continue;

            // K fragments: global (L2-resident) -> VGPR
            bf16x8 kf0[4], kf1[4];
#pragma unroll
            for (int jl = 0; jl < 4; ++jl) {
                const size_t krow = (size_t)(k0 + (jb + jl) * 16 + fr) * 64;
                kf0[jl] = *(const bf16x8*)(kp + krow + fk);
                kf1[jl] = *(const bf16x8*)(kp + krow + 32 + fk);
            }
            // V fragments: issue early, latency hides under QK^T + exp
            bf16x8 vf[2][4];
#pragma unroll
            for (int kl = 0; kl < 2; ++kl)
#pragma unroll
                for (int j4 = 0; j4 < 4; ++j4)
                    vf[kl][j4] = *(const bf16x8*)(vp + (size_t)(j4 * 16 + fr) * 2048
                                                  + k0 + half * 64 + kl * 32 + fk);

            // S^T = K Q^T : 4 key-tiles, K fragments reused for both strips
            f32x4 sA[4], sB[4];
#pragma unroll
            for (int jl = 0; jl < 4; ++jl) {
                f32x4 zA = (f32x4){0.f, 0.f, 0.f, 0.f};
                f32x4 zB = (f32x4){0.f, 0.f, 0.f, 0.f};
                zA = __builtin_amdgcn_mfma_f32_16x16x32_bf16(kf0[jl], qfA0, zA, 0, 0, 0);
                zA = __builtin_amdgcn_mfma_f32_16x16x32_bf16(kf1[jl], qfA1, zA, 0, 0, 0);
                zB = __builtin_amdgcn_mfma_f32_16x16x32_bf16(kf0[jl], qfB0, zB, 0, 0, 0);
                zB = __builtin_amdgcn_mfma_f32_16x16x32_bf16(kf1[jl], qfB1, zB, 0, 0, 0);
                sA[jl] = zA;
                sB[jl] = zB;
            }
            if (!lastIt) {        // interior: no mask
#pragma unroll
                for (int jl = 0; jl < 4; ++jl)
#pragma unroll
                    for (int r = 0; r < 4; ++r) {
                        float pA = __expf(sA[jl][r]);
                        float pB = __expf(sB[jl][r]);
                        sA[jl][r] = pA; lsumA += pA;
                        sB[jl][r] = pB; lsumB += pB;
                    }
            } else {              // diagonal chunk: key > q masked per strip
#pragma unroll
                for (int jl = 0; jl < 4; ++jl)
#pragma unroll
                    for (int r = 0; r < 4; ++r) {
                        const int key = k0 + (jb + jl) * 16 + fq * 4 + r;
                        float vA = (key > qrowA)      ? NEG_BIG : sA[jl][r];
                        float vB = (key > qrowA + 16) ? NEG_BIG : sB[jl][r];
                        float pA = __expf(vA);
                        float pB = __expf(vB);
                        sA[jl][r] = pA; lsumA += pA;
                        sB[jl][r] = pB; lsumB += pB;
                    }
            }

            // Ps: lane holds 4 consecutive local keys per tile -> b64 writes
#pragma unroll
            for (int jl = 0; jl < 4; ++jl) {
                uint2 uA, uB;
                uA.x = cvtpk(sA[jl][0], sA[jl][1]);
                uA.y = cvtpk(sA[jl][2], sA[jl][3]);
                uB.x = cvtpk(sB[jl][0], sB[jl][1]);
                uB.y = cvtpk(sB[jl][2], sB[jl][3]);
                *(uint2*)(pw + fr * LPP + jl * 16 + fq * 4)        = uA;
                *(uint2*)(pw + (16 + fr) * LPP + jl * 16 + fq * 4) = uB;
            }
            __asm__ volatile("" ::: "memory");

            // PV: A-frags from Ps (b128), B-frags = vf (already in regs)
#pragma unroll
            for (int kl = 0; kl < 2; ++kl) {
                bf16x8 pfA = *(const bf16x8*)(pw + fr * LPP + kl * 32 + fk);
                bf16x8 pfB = *(const bf16x8*)(pw + (16 + fr) * LPP + kl * 32 + fk);
#pragma unroll
                for (int j4 = 0; j4 < 4; ++j4) {
                    oA[j4] = __builtin_amdgcn_mfma_f32_16x16x32_bf16(pfA, vf[kl][j4], oA[j4], 0, 0, 0);
                    oB[j4] = __builtin_amdgcn_mfma_f32_16x16x32_bf16(pfB, vf[kl][j4], oB[j4], 0, 0, 0);
                }
            }
        }

        // ---- epilogue: combine key-half wave pairs, per strip -------------
        lsumA += __shfl_xor(lsumA, 16, 64);
        lsumA += __shfl_xor(lsumA, 32, 64);
        lsumB += __shfl_xor(lsumB, 16, 64);
        lsumB += __shfl_xor(lsumB, 32, 64);

        __syncthreads();   // all Ps use done -> reuse SM as fp32 exchange
        float* exA = (float*)SM + (wq * 2) * 1104;   // 8 regions x 4416 B
        float* exB = exA + 1104;
        if (half) {
#pragma unroll
            for (int j4 = 0; j4 < 4; ++j4)
#pragma unroll
                for (int r = 0; r < 4; ++r) {
                    exA[lane * 17 + j4 * 4 + r] = oA[j4][r];
                    exB[lane * 17 + j4 * 4 + r] = oB[j4][r];
                }
            if (fq == 0) {
                exA[1088 + fr] = lsumA;
                exB[1088 + fr] = lsumB;
            }
        }
        __syncthreads();
        if (!half) {
            float linvA[4], linvB[4];
#pragma unroll
            for (int r = 0; r < 4; ++r) {
                float ownA = __shfl(lsumA, fq * 4 + r, 64);
                float ownB = __shfl(lsumB, fq * 4 + r, 64);
                linvA[r] = 1.0f / (ownA + exA[1088 + fq * 4 + r]);
                linvB[r] = 1.0f / (ownB + exB[1088 + fq * 4 + r]);
            }
#pragma unroll
            for (int j4 = 0; j4 < 4; j4 += 2)
#pragma unroll
                for (int r = 0; r < 4; ++r) {
                    int rowA = qb * 128 + wq * 32 + fq * 4 + r;
                    size_t ybA = ((size_t)b * 2048 + rowA) * 1024 + h * 64;
                    float a0 = (oA[j4][r]     + exA[lane * 17 + j4 * 4 + r])       * linvA[r];
                    float a1 = (oA[j4 + 1][r] + exA[lane * 17 + (j4 + 1) * 4 + r]) * linvA[r];
                    unsigned ua = cvtpk(a0, a1);
                    y[ybA + j4 * 16 + fr]       = (ushort)(ua & 0xFFFFu);
                    y[ybA + (j4 + 1) * 16 + fr] = (ushort)(ua >> 16);

                    size_t ybB = ybA + (size_t)16 * 1024;
                    float b0 = (oB[j4][r]     + exB[lane * 17 + j4 * 4 + r])       * linvB[r];
                    float b1 = (oB[j4 + 1][r] + exB[lane * 17 + (j4 + 1) * 4 + r]) * linvB[r];
                    unsigned ub = cvtpk(b0, b1);
                    y[ybB + j4 * 16 + fr]       = (ushort)(ub & 0xFFFFu);
                    y[ybB + (j4 + 1) * 16 + fr] = (ushort)(ub >> 16);
                }
        }
    }
}

// ---------------------------------------------------------------------------
extern "C" void kernel_launch(void* const* d_in, const int* in_sizes, int n_in,
                              void* d_out, int out_size, void* d_ws, size_t ws_size,
                              hipStream_t stream) {
    const int nx = in_sizes[0];   // 4194304
    const int na = in_sizes[1];   // 3145728
    const int np = in_sizes[2];   // 1048576

    ushort* qkvh = (ushort*)d_ws;                      // q,k: [2][16][2048][64]; v: [2][16][64][2048]
    ushort* yb   = qkvh + (size_t)3 * 4194304;
    ushort* xb   = yb + (size_t)4096 * 1024;
    ushort* wab  = xb + nx;
    ushort* wpb  = wab + na;
    size_t need = ((size_t)3 * 4194304 + (size_t)4096 * 1024 + nx + na + np) * 2;
    if (ws_size < need) return;

    tobf16_all_kernel<<<dim3(4096), 256, 0, stream>>>(
        (const unsigned*)d_in[0], (const unsigned*)d_in[1], (const unsigned*)d_in[2],
        xb, wab, wpb);

    gemm_qkv_rope_kernel<<<dim3(32, 24), 256, 0, stream>>>(xb, wab, qkvh, 1024);
    attn_kernel<<<dim3(8, 32), 512, 0, stream>>>(qkvh, yb);
    gemm_bt_kernel<<<dim3(32, 8), 256, 0, stream>>>(yb, wpb, (float*)d_out, 4096, 1024, 1024);
}

// Round 11
// 178.601 us; speedup vs baseline: 1.1844x; 1.1844x over previous
//
#include <hip/hip_runtime.h>
#include <math.h>

typedef __bf16 bf16x8 __attribute__((ext_vector_type(8)));
typedef float f32x4 __attribute__((ext_vector_type(4)));

__device__ __forceinline__ unsigned f2bf(float f) {
    union { float f; unsigned u; } v; v.f = f;
    return (v.u + 0x7FFFu + ((v.u >> 16) & 1u)) >> 16;
}

// packed fp32->bf16 (RNE), 2 values in 1 op: lo=a, hi=b
__device__ __forceinline__ unsigned cvtpk(float a, float b) {
    unsigned r;
    __asm__("v_cvt_pk_bf16_f32 %0, %1, %2" : "=v"(r) : "v"(a), "v"(b));
    return r;
}

// async global->LDS, 16B per lane. LDS dest = wave-uniform base + lane*16.
__device__ __forceinline__ void gload16(const ushort* g, ushort* l) {
    __builtin_amdgcn_global_load_lds(
        (const __attribute__((address_space(1))) void*)g,
        (__attribute__((address_space(3))) void*)l, 16, 0, 0);
}

// ---------------------------------------------------------------------------
// Fused input canonicalization (one launch): fp32 -> bf16 for all 3 inputs.
// ---------------------------------------------------------------------------
__device__ __forceinline__ bool src_is_fp32(const unsigned* s) {
    int sane = 0;
#pragma unroll
    for (int i = 0; i < 64; ++i) {
        unsigned lo = s[i] & 0xFFFFu;
        unsigned e = (lo >> 7) & 0xFF;
        if (lo == 0u || (e >= 100u && e <= 140u)) sane++;
    }
    return sane < 48;
}

__global__ __launch_bounds__(256) void tobf16_all_kernel(
    const unsigned* __restrict__ s0, const unsigned* __restrict__ s1,
    const unsigned* __restrict__ s2,
    ushort* __restrict__ d0, ushort* __restrict__ d1, ushort* __restrict__ d2) {
    const int bx = blockIdx.x;
    const unsigned* src;
    ushort* dst;
    int lb;
    if (bx < 2048)      { src = s0; dst = d0; lb = bx; }
    else if (bx < 3584) { src = s1; dst = d1; lb = bx - 2048; }
    else                { src = s2; dst = d2; lb = bx - 3584; }
    const int i = lb * 2048 + threadIdx.x * 8;
    if (src_is_fp32(src)) {
        const float* fs = (const float*)src;
        float4 f0 = *(const float4*)(fs + i);
        float4 f1 = *(const float4*)(fs + i + 4);
        uint4 o;
        o.x = f2bf(f0.x) | (f2bf(f0.y) << 16);
        o.y = f2bf(f0.z) | (f2bf(f0.w) << 16);
        o.z = f2bf(f1.x) | (f2bf(f1.y) << 16);
        o.w = f2bf(f1.z) | (f2bf(f1.w) << 16);
        *(uint4*)(dst + i) = o;
    } else {
        *(uint4*)(dst + i) = *(const uint4*)((const ushort*)src + i);
    }
}

// ---------------------------------------------------------------------------
// GEMM K-loop: double-buffered LDS + global_load_lds issued one compute-phase
// ahead of its consuming barrier (validated win, round 10).
// ---------------------------------------------------------------------------
constexpr int GBM = 128, GBN = 128, GBK = 32;

// ---- GEMM1 + RoPE + head-major remap; V written TRANSPOSED [b][h][d][t] ---
__global__ __launch_bounds__(256) void gemm_qkv_rope_kernel(
    const ushort* __restrict__ A, const ushort* __restrict__ Bmat,
    ushort* __restrict__ qkvh, int K) {
    __shared__ ushort As[2][GBM * GBK];
    __shared__ ushort Bs[2][GBN * GBK];

    const int tid  = threadIdx.x;
    const int lane = tid & 63;
    const int wv   = tid >> 6;
    const int wm   = (wv >> 1) * 64;
    const int wn   = (wv & 1) * 64;

    const ushort* Ab = A + (size_t)blockIdx.x * GBM * K;
    const ushort* Bb = Bmat + (size_t)blockIdx.y * GBN * K;

    f32x4 acc[4][4];
#pragma unroll
    for (int i = 0; i < 4; i++)
#pragma unroll
        for (int j = 0; j < 4; j++) acc[i][j] = (f32x4){0.f, 0.f, 0.f, 0.f};

    const int srow = tid >> 2;
    const int scol = (tid & 3) * 8;
    const int fr = lane & 15;
    const int fk = (lane >> 4) * 8;
    const int nK = K >> 5;

    gload16(Ab + (size_t)srow * K + scol,        As[0] + wv * 512);
    gload16(Ab + (size_t)(srow + 64) * K + scol, As[0] + wv * 512 + 2048);
    gload16(Bb + (size_t)srow * K + scol,        Bs[0] + wv * 512);
    gload16(Bb + (size_t)(srow + 64) * K + scol, Bs[0] + wv * 512 + 2048);

#pragma unroll 1
    for (int it = 0; it < nK; ++it) {
        const int cur = it & 1;
        __syncthreads();
        if (it + 1 < nK) {
            const int k0 = (it + 1) << 5, nxt = cur ^ 1;
            gload16(Ab + (size_t)srow * K + k0 + scol,        As[nxt] + wv * 512);
            gload16(Ab + (size_t)(srow + 64) * K + k0 + scol, As[nxt] + wv * 512 + 2048);
            gload16(Bb + (size_t)srow * K + k0 + scol,        Bs[nxt] + wv * 512);
            gload16(Bb + (size_t)(srow + 64) * K + k0 + scol, Bs[nxt] + wv * 512 + 2048);
        }
        bf16x8 af[4], bfr[4];
#pragma unroll
        for (int i = 0; i < 4; i++)
            af[i] = *(const bf16x8*)(As[cur] + (wm + i * 16 + fr) * GBK + fk);
#pragma unroll
        for (int j = 0; j < 4; j++)
            bfr[j] = *(const bf16x8*)(Bs[cur] + (wn + j * 16 + fr) * GBK + fk);
#pragma unroll
        for (int i = 0; i < 4; i++)
#pragma unroll
            for (int j = 0; j < 4; j++)
                acc[i][j] = __builtin_amdgcn_mfma_f32_16x16x32_bf16(af[i], bfr[j], acc[i][j], 0, 0, 0);
    }

    const int crow0 = (lane >> 4) * 4;
    const int col0  = blockIdx.y * GBN + wn;       // 64-aligned
    const int which = col0 >> 10;                  // 0=q 1=k 2=v
    const int hh    = (col0 >> 6) & 15;

    if (which < 2) {
        ushort* outp = qkvh + (size_t)which * 4194304 + (size_t)hh * 131072;
        const float inva = exp2f((float)fr * -0.41524101186f);
        const float invb = exp2f((float)(fr + 16) * -0.41524101186f);
        const float qs = (which == 0) ? 0.125f : 1.0f;
#pragma unroll
        for (int i = 0; i < 4; i++)
#pragma unroll
            for (int r = 0; r < 4; r++) {
                int row = blockIdx.x * GBM + wm + i * 16 + crow0 + r;
                int t = row & 2047;
                size_t ob = ((size_t)(row >> 11)) * 2097152 + (size_t)t * 64;
                float sa, ca, sb, cb;
                __sincosf((float)t * inva, &sa, &ca);
                __sincosf((float)t * invb, &sb, &cb);
                float q0 = acc[i][0][r], q1 = acc[i][1][r];
                float q2 = acc[i][2][r], q3 = acc[i][3][r];
                float n0 = (q0 * ca + q2 * sa) * qs;
                float n1 = (q1 * cb + q3 * sb) * qs;
                float n2 = (q2 * ca - q0 * sa) * qs;
                float n3 = (q3 * cb - q1 * sb) * qs;
                unsigned u01 = cvtpk(n0, n1);
                unsigned u23 = cvtpk(n2, n3);
                outp[ob + fr]      = (ushort)(u01 & 0xFFFFu);
                outp[ob + 16 + fr] = (ushort)(u01 >> 16);
                outp[ob + 32 + fr] = (ushort)(u23 & 0xFFFFu);
                outp[ob + 48 + fr] = (ushort)(u23 >> 16);
            }
    } else {
        // V: transposed layout [b][h][d=64][t=2048]; 4 consecutive t packed
        const int row0 = blockIdx.x * GBM;   // whole block in one b
        ushort* vout = qkvh + (size_t)2 * 4194304
                     + ((size_t)(row0 >> 11)) * 2097152 + (size_t)hh * 131072;
#pragma unroll
        for (int i = 0; i < 4; i++) {
            const int t0 = (blockIdx.x * GBM + wm + i * 16 + crow0) & 2047;
#pragma unroll
            for (int j = 0; j < 4; j++) {
                uint2 u;
                u.x = cvtpk(acc[i][j][0], acc[i][j][1]);
                u.y = cvtpk(acc[i][j][2], acc[i][j][3]);
                *(uint2*)(vout + (size_t)(j * 16 + fr) * 2048 + t0) = u;
            }
        }
    }
}

// ---- out-projection GEMM (fp32 out), same dbuf loop -----------------------
__global__ __launch_bounds__(256) void gemm_bt_kernel(
    const ushort* __restrict__ A, const ushort* __restrict__ Bmat,
    float* __restrict__ C, int M, int N, int K) {
    __shared__ ushort As[2][GBM * GBK];
    __shared__ ushort Bs[2][GBN * GBK];

    const int tid  = threadIdx.x;
    const int lane = tid & 63;
    const int wv   = tid >> 6;
    const int wm   = (wv >> 1) * 64;
    const int wn   = (wv & 1) * 64;

    const ushort* Ab = A + (size_t)blockIdx.x * GBM * K;
    const ushort* Bb = Bmat + (size_t)blockIdx.y * GBN * K;

    f32x4 acc[4][4];
#pragma unroll
    for (int i = 0; i < 4; i++)
#pragma unroll
        for (int j = 0; j < 4; j++) acc[i][j] = (f32x4){0.f, 0.f, 0.f, 0.f};

    const int srow = tid >> 2;
    const int scol = (tid & 3) * 8;
    const int fr = lane & 15;
    const int fk = (lane >> 4) * 8;
    const int nK = K >> 5;

    gload16(Ab + (size_t)srow * K + scol,        As[0] + wv * 512);
    gload16(Ab + (size_t)(srow + 64) * K + scol, As[0] + wv * 512 + 2048);
    gload16(Bb + (size_t)srow * K + scol,        Bs[0] + wv * 512);
    gload16(Bb + (size_t)(srow + 64) * K + scol, Bs[0] + wv * 512 + 2048);

#pragma unroll 1
    for (int it = 0; it < nK; ++it) {
        const int cur = it & 1;
        __syncthreads();
        if (it + 1 < nK) {
            const int k0 = (it + 1) << 5, nxt = cur ^ 1;
            gload16(Ab + (size_t)srow * K + k0 + scol,        As[nxt] + wv * 512);
            gload16(Ab + (size_t)(srow + 64) * K + k0 + scol, As[nxt] + wv * 512 + 2048);
            gload16(Bb + (size_t)srow * K + k0 + scol,        Bs[nxt] + wv * 512);
            gload16(Bb + (size_t)(srow + 64) * K + k0 + scol, Bs[nxt] + wv * 512 + 2048);
        }
        bf16x8 af[4], bfr[4];
#pragma unroll
        for (int i = 0; i < 4; i++)
            af[i] = *(const bf16x8*)(As[cur] + (wm + i * 16 + fr) * GBK + fk);
#pragma unroll
        for (int j = 0; j < 4; j++)
            bfr[j] = *(const bf16x8*)(Bs[cur] + (wn + j * 16 + fr) * GBK + fk);
#pragma unroll
        for (int i = 0; i < 4; i++)
#pragma unroll
            for (int j = 0; j < 4; j++)
                acc[i][j] = __builtin_amdgcn_mfma_f32_16x16x32_bf16(af[i], bfr[j], acc[i][j], 0, 0, 0);
    }

    const int crow0 = (lane >> 4) * 4;
#pragma unroll
    for (int i = 0; i < 4; i++)
#pragma unroll
        for (int j = 0; j < 4; j++)
#pragma unroll
            for (int r = 0; r < 4; r++) {
                int row = blockIdx.x * GBM + wm + i * 16 + crow0 + r;
                int col = blockIdx.y * GBN + wn + j * 16 + fr;
                C[(size_t)row * N + col] = acc[i][j][r];
            }
}

// ---------------------------------------------------------------------------
// Causal flash attention v17 = v15 (validated best, r9: total 179.06us)
// + diagonal compute-skip: on the last (diagonal) iter, waves with
// half==1 && wq<2 are fully masked (keys k0+64..k0+127 > all their q-rows;
// exp(NEG_BIG)=0 contribution), so they skip QK^T/exp/Ps/PV while still
// performing staging and barriers. r10's L2-direct experiment is reverted:
// LDS staging is what makes 8-wave K/V reuse cheap (L1/VMEM path regressed
// 2x). Everything else identical to v15.
// ---------------------------------------------------------------------------
#define NEG_BIG (-1e30f)
constexpr int LPP    = 72;       // Ps row: 64 keys + 8 pad
constexpr int VT_OFF = 16384;    // ushorts: Ks[2][8192]
constexpr int PS_OFF = 32768;    // ushorts: Vt[2][8192]

__global__ __launch_bounds__(512) void attn_kernel(const ushort* __restrict__ qkvh,
                                                   ushort* __restrict__ y) {
    __shared__ ushort SM[PS_OFF + 8 * 32 * LPP];   // 51200 ushorts = 102400 B

    const int tid  = threadIdx.x;
    const int lane = tid & 63;
    const int wv   = tid >> 6;          // 0..7
    const int half = wv >> 2;           // 0: keys 0..63, 1: keys 64..127
    const int wq   = wv & 3;            // 32-row q-group
    const int jb   = half * 4;          // key-tile base

    // T1: bijective XCD swizzle (grid (8,32) -> 256 blocks, XCD = id&7)
    const int id   = blockIdx.x + (blockIdx.y << 3);
    const int xcd  = id & 7;
    const int k8   = id >> 3;           // 0..31
    const int bh   = xcd * 4 + (k8 & 3);
    const int pid  = k8 >> 2;           // 0..7
    const int b    = bh >> 4, h = bh & 15;

    const ushort* qp = qkvh + (size_t)b * 2097152 + (size_t)h * 131072;
    const ushort* kp = qp + 4194304;    // K [t][64]
    const ushort* vp = qp + 8388608;    // V^T [d][2048]

    const int fr = lane & 15;
    const int fq = lane >> 4;
    const int fk = fq * 8;

    // K staging sources (pre-swizzled, ushorts); dest = linear tid*8
    const int ksrcA = (tid >> 3) * 64 + (((tid & 7) ^ ((tid >> 3) & 7)) << 3);
    const int ksrcB = ksrcA + 4096;     // keys +64, same 3-bit xor
    // V^T staging sources: d = tid>>4 (+32), blk = tid&15, blk' = blk^(d&15)
    const int vsrcA = (tid >> 4) * 2048 + (((tid & 15) ^ ((tid >> 4) & 15)) << 3);
    const int vsrcB = vsrcA + 65536;    // d +32, same 4-bit xor
    // QK^T swizzled read offsets (per-lane constants)
    const int koff0 = (fq ^ (fr & 7)) << 3;
    const int koff1 = koff0 ^ 32;
    // PV V^T read offsets: block bo = half*8 + kl*4 + fq, unswizzle ^fr
    const int voff0 = ((half * 8 + fq) ^ fr) << 3;
    const int voff1 = ((half * 8 + 4 + fq) ^ fr) << 3;

    ushort* pw = SM + PS_OFF + wv * (32 * LPP);

#pragma unroll 1
    for (int seg = 0; seg < 2; ++seg) {
        const int qb = seg ? (15 - pid) : pid;    // 128-row q-block, 0..15
        const int nIt = qb + 1;

        __syncthreads();   // previous seg epilogue readers done

        // stage chunk 0 -> buf 0 (4 async DMA ops, drained by first barrier)
        gload16(kp + ksrcA, SM + wv * 512);
        gload16(kp + ksrcB, SM + 4096 + wv * 512);
        gload16(vp + vsrcA, SM + VT_OFF + wv * 512);
        gload16(vp + vsrcB, SM + VT_OFF + 4096 + wv * 512);

        const int qrowA = qb * 128 + wq * 32 + fr;
        bf16x8 qfA0 = *(const bf16x8*)(qp + (size_t)qrowA * 64 + fk);
        bf16x8 qfA1 = *(const bf16x8*)(qp + (size_t)qrowA * 64 + 32 + fk);
        bf16x8 qfB0 = *(const bf16x8*)(qp + (size_t)(qrowA + 16) * 64 + fk);
        bf16x8 qfB1 = *(const bf16x8*)(qp + (size_t)(qrowA + 16) * 64 + 32 + fk);

        f32x4 oA[4], oB[4];
#pragma unroll
        for (int j4 = 0; j4 < 4; ++j4) {
            oA[j4] = (f32x4){0.f, 0.f, 0.f, 0.f};
            oB[j4] = (f32x4){0.f, 0.f, 0.f, 0.f};
        }
        float lsumA = 0.f, lsumB = 0.f;

#pragma unroll 1
        for (int it = 0; it < nIt; ++it) {
            const int cur = it & 1;
            const int k0 = it * 128;
            const ushort* Ksc = SM + cur * 8192;
            const ushort* Vtc = SM + VT_OFF + cur * 8192;
            __syncthreads();   // buf[cur] staged; buf[cur^1] readers done
            if (it + 1 < nIt) {
                const int nxt = cur ^ 1;
                gload16(kp + (it + 1) * 8192 + ksrcA, SM + nxt * 8192 + wv * 512);
                gload16(kp + (it + 1) * 8192 + ksrcB, SM + nxt * 8192 + 4096 + wv * 512);
                gload16(vp + (it + 1) * 128 + vsrcA, SM + VT_OFF + nxt * 8192 + wv * 512);
                gload16(vp + (it + 1) * 128 + vsrcB, SM + VT_OFF + nxt * 8192 + 4096 + wv * 512);
            }

            const bool lastIt = (it + 1 == nIt);
            // diagonal iter: keys k0+64..k0+127 exceed all rows of the wq<2
            // strips -> those waves' contribution is exp(-1e30)=0. Skip the
            // compute (staging+barriers above already done).
            if (lastIt && half && (wq < 2)) continue;

            // S^T = K Q^T : 4 key-tiles, K fragments reused for both strips
            f32x4 sA[4], sB[4];
#pragma unroll
            for (int jl = 0; jl < 4; ++jl) {
                const int row = ((jb + jl) * 16 + fr) * 64;
                bf16x8 kf0 = *(const bf16x8*)(Ksc + row + koff0);
                bf16x8 kf1 = *(const bf16x8*)(Ksc + row + koff1);
                f32x4 zA = (f32x4){0.f, 0.f, 0.f, 0.f};
                f32x4 zB = (f32x4){0.f, 0.f, 0.f, 0.f};
                zA = __builtin_amdgcn_mfma_f32_16x16x32_bf16(kf0, qfA0, zA, 0, 0, 0);
                zA = __builtin_amdgcn_mfma_f32_16x16x32_bf16(kf1, qfA1, zA, 0, 0, 0);
                zB = __builtin_amdgcn_mfma_f32_16x16x32_bf16(kf0, qfB0, zB, 0, 0, 0);
                zB = __builtin_amdgcn_mfma_f32_16x16x32_bf16(kf1, qfB1, zB, 0, 0, 0);
                sA[jl] = zA;
                sB[jl] = zB;
            }
            if (!lastIt) {        // interior: no mask
#pragma unroll
                for (int jl = 0; jl < 4; ++jl)
#pragma unroll
                    for (int r = 0; r < 4; ++r) {
                        float pA = __expf(sA[jl][r]);
                        float pB = __expf(sB[jl][r]);
                        sA[jl][r] = pA; lsumA += pA;
                        sB[jl][r] = pB; lsumB += pB;
                    }
            } else {              // diagonal chunk: key > q masked per strip
#pragma unroll
                for (int jl = 0; jl < 4; ++jl)
#pragma unroll
                    for (int r = 0; r < 4; ++r) {
                        const int key = k0 + (jb + jl) * 16 + fq * 4 + r;
                        float vA = (key > qrowA)      ? NEG_BIG : sA[jl][r];
                        float vB = (key > qrowA + 16) ? NEG_BIG : sB[jl][r];
                        float pA = __expf(vA);
                        float pB = __expf(vB);
                        sA[jl][r] = pA; lsumA += pA;
                        sB[jl][r] = pB; lsumB += pB;
                    }
            }

            // Ps: lane holds 4 consecutive local keys per tile -> b64 writes
#pragma unroll
            for (int jl = 0; jl < 4; ++jl) {
                uint2 uA, uB;
                uA.x = cvtpk(sA[jl][0], sA[jl][1]);
                uA.y = cvtpk(sA[jl][2], sA[jl][3]);
                uB.x = cvtpk(sB[jl][0], sB[jl][1]);
                uB.y = cvtpk(sB[jl][2], sB[jl][3]);
                *(uint2*)(pw + fr * LPP + jl * 16 + fq * 4)        = uA;
                *(uint2*)(pw + (16 + fr) * LPP + jl * 16 + fq * 4) = uB;
            }
            __asm__ volatile("" ::: "memory");

            // PV: V fragments read once, reused for both strips
#pragma unroll
            for (int kl = 0; kl < 2; ++kl) {
                bf16x8 pfA = *(const bf16x8*)(pw + fr * LPP + kl * 32 + fk);
                bf16x8 pfB = *(const bf16x8*)(pw + (16 + fr) * LPP + kl * 32 + fk);
                const int voff = kl ? voff1 : voff0;
#pragma unroll
                for (int j4 = 0; j4 < 4; ++j4) {
                    bf16x8 vf = *(const bf16x8*)(Vtc + (j4 * 16 + fr) * 128 + voff);
                    oA[j4] = __builtin_amdgcn_mfma_f32_16x16x32_bf16(pfA, vf, oA[j4], 0, 0, 0);
                    oB[j4] = __builtin_amdgcn_mfma_f32_16x16x32_bf16(pfB, vf, oB[j4], 0, 0, 0);
                }
            }
        }

        // ---- epilogue: combine key-half wave pairs, per strip -------------
        lsumA += __shfl_xor(lsumA, 16, 64);
        lsumA += __shfl_xor(lsumA, 32, 64);
        lsumB += __shfl_xor(lsumB, 16, 64);
        lsumB += __shfl_xor(lsumB, 32, 64);

        __syncthreads();   // all Ps/Vt/Ks reads done -> reuse Ps as exchange
        float* exA = (float*)(SM + PS_OFF) + (wq * 2) * 1104;
        float* exB = exA + 1104;
        if (half) {
#pragma unroll
            for (int j4 = 0; j4 < 4; ++j4)
#pragma unroll
                for (int r = 0; r < 4; ++r) {
                    exA[lane * 17 + j4 * 4 + r] = oA[j4][r];
                    exB[lane * 17 + j4 * 4 + r] = oB[j4][r];
                }
            if (fq == 0) {
                exA[1088 + fr] = lsumA;
                exB[1088 + fr] = lsumB;
            }
        }
        __syncthreads();
        if (!half) {
            float linvA[4], linvB[4];
#pragma unroll
            for (int r = 0; r < 4; ++r) {
                float ownA = __shfl(lsumA, fq * 4 + r, 64);
                float ownB = __shfl(lsumB, fq * 4 + r, 64);
                linvA[r] = 1.0f / (ownA + exA[1088 + fq * 4 + r]);
                linvB[r] = 1.0f / (ownB + exB[1088 + fq * 4 + r]);
            }
#pragma unroll
            for (int j4 = 0; j4 < 4; j4 += 2)
#pragma unroll
                for (int r = 0; r < 4; ++r) {
                    int rowA = qb * 128 + wq * 32 + fq * 4 + r;
                    size_t ybA = ((size_t)b * 2048 + rowA) * 1024 + h * 64;
                    float a0 = (oA[j4][r]     + exA[lane * 17 + j4 * 4 + r])       * linvA[r];
                    float a1 = (oA[j4 + 1][r] + exA[lane * 17 + (j4 + 1) * 4 + r]) * linvA[r];
                    unsigned ua = cvtpk(a0, a1);
                    y[ybA + j4 * 16 + fr]       = (ushort)(ua & 0xFFFFu);
                    y[ybA + (j4 + 1) * 16 + fr] = (ushort)(ua >> 16);

                    size_t ybB = ybA + (size_t)16 * 1024;
                    float b0 = (oB[j4][r]     + exB[lane * 17 + j4 * 4 + r])       * linvB[r];
                    float b1 = (oB[j4 + 1][r] + exB[lane * 17 + (j4 + 1) * 4 + r]) * linvB[r];
                    unsigned ub = cvtpk(b0, b1);
                    y[ybB + j4 * 16 + fr]       = (ushort)(ub & 0xFFFFu);
                    y[ybB + (j4 + 1) * 16 + fr] = (ushort)(ub >> 16);
                }
        }
    }
}

// ---------------------------------------------------------------------------
extern "C" void kernel_launch(void* const* d_in, const int* in_sizes, int n_in,
                              void* d_out, int out_size, void* d_ws, size_t ws_size,
                              hipStream_t stream) {
    const int nx = in_sizes[0];   // 4194304
    const int na = in_sizes[1];   // 3145728
    const int np = in_sizes[2];   // 1048576

    ushort* qkvh = (ushort*)d_ws;                      // q,k: [2][16][2048][64]; v: [2][16][64][2048]
    ushort* yb   = qkvh + (size_t)3 * 4194304;
    ushort* xb   = yb + (size_t)4096 * 1024;
    ushort* wab  = xb + nx;
    ushort* wpb  = wab + na;
    size_t need = ((size_t)3 * 4194304 + (size_t)4096 * 1024 + nx + na + np) * 2;
    if (ws_size < need) return;

    tobf16_all_kernel<<<dim3(4096), 256, 0, stream>>>(
        (const unsigned*)d_in[0], (const unsigned*)d_in[1], (const unsigned*)d_in[2],
        xb, wab, wpb);

    gemm_qkv_rope_kernel<<<dim3(32, 24), 256, 0, stream>>>(xb, wab, qkvh, 1024);
    attn_kernel<<<dim3(8, 32), 512, 0, stream>>>(qkvh, yb);
    gemm_bt_kernel<<<dim3(32, 8), 256, 0, stream>>>(yb, wpb, (float*)d_out, 4096, 1024, 1024);
}